// Round 1
// baseline (8384.660 us; speedup 1.0000x reference)
//
#include <hip/hip_runtime.h>
#include <string.h>

// Problem constants
#define TT    256      // sequence length
#define BBATCH 256     // batch
#define EE    512      // embedding dim
#define HH    1024     // hidden dim
#define G4    4096     // 4*H
#define KTOT  1536     // H + E (concatenated K)

// Tiling
#define BM   64        // batch tile per block
#define BN   16        // j (hidden-unit) tile per block (per gate)
#define BK   64        // K chunk
#define APAD 8         // LDS pad (elems) to spread banks

typedef __attribute__((ext_vector_type(8))) short short8;
typedef __attribute__((ext_vector_type(4))) float f32x4;

__device__ __forceinline__ short f2bf(float f) {
    unsigned u; __builtin_memcpy(&u, &f, 4);
    unsigned r = (u + 0x7FFFu + ((u >> 16) & 1u)) >> 16;   // RNE
    return (short)(unsigned short)r;
}
__device__ __forceinline__ float bf2f(short s) {
    unsigned u = ((unsigned)(unsigned short)s) << 16;
    float f; __builtin_memcpy(&f, &u, 4);
    return f;
}
__device__ __forceinline__ float sigf(float x) { return 1.f / (1.f + __expf(-x)); }

// ---------------------------------------------------------------------------
// Prep: w_cat[r][0:1024]=w_hh[r], w_cat[r][1024:1536]=w_ih[r] (bf16);
//       bias[r] = b_ih[r] + b_hh[r]
// ---------------------------------------------------------------------------
__global__ __launch_bounds__(256) void prep_kernel(
    const float* __restrict__ w_ih, const float* __restrict__ w_hh,
    const float* __restrict__ b_ih, const float* __restrict__ b_hh,
    short* __restrict__ w_cat, float* __restrict__ bias)
{
    int r = blockIdx.x;            // 0..4095
    int tid = threadIdx.x;
    for (int c = tid; c < KTOT; c += 256) {
        float v = (c < HH) ? w_hh[(size_t)r * HH + c]
                           : w_ih[(size_t)r * EE + (c - HH)];
        w_cat[(size_t)r * KTOT + c] = f2bf(v);
    }
    if (tid == 0) bias[r] = b_ih[r] + b_hh[r];
}

// ---------------------------------------------------------------------------
// One LSTM time step. Grid (4 batch-tiles, 64 j-tiles), 256 threads = 4 waves.
// Wave g computes gate g's [BM x BN] tile of  [h|x] @ W^T  via MFMA, then the
// block applies the elementwise cell update for its (b, j) patch.
// MFMA 16x16x32 bf16 layouts (HW-verified per guide):
//   A: lane holds A[m=lane&15][k=(lane>>4)*8 + 0..7]
//   B: lane holds B[k=(lane>>4)*8 + 0..7][n=lane&15]
//   D: lane holds D[m=(lane>>4)*4 + r][n=lane&15]
// ---------------------------------------------------------------------------
__global__ __launch_bounds__(256) void lstm_step(
    const short* __restrict__ w_cat,   // [4096][1536] bf16
    const float* __restrict__ bias,    // [4096]
    const int*   __restrict__ text,    // [B][T]
    const float* __restrict__ emb,     // [VOCAB][512]
    const short* __restrict__ h_in,    // [B][H] bf16
    short*       __restrict__ h_out,   // [B][H] bf16
    float*       __restrict__ c_st,    // [B][H] f32
    int t)
{
    __shared__ short At[BM][BK + APAD];        // 64 x 72 bf16 = 9216 B
    __shared__ float Gt[4][BM][BN + 1];        // 4 x 64 x 17 f32 = 17408 B

    const int tid  = threadIdx.x;
    const int wv   = tid >> 6;                 // gate index 0..3 (i,f,g,o)
    const int lane = tid & 63;
    const int b0   = blockIdx.x * BM;          // batch tile origin
    const int j0   = blockIdx.y * BN;          // hidden-unit tile origin
    const int n    = lane & 15;
    const int q    = lane >> 4;

    f32x4 acc[4];
    #pragma unroll
    for (int i = 0; i < 4; ++i) acc[i] = (f32x4){0.f, 0.f, 0.f, 0.f};

    // A staging: 256 threads load 64x64 elems, 16 per thread
    const int ar = tid >> 2;                   // row 0..63
    const int ac = (tid & 3) * 16;             // col 0/16/32/48
    const int ab = b0 + ar;
    const long erow = (long)text[(size_t)ab * TT + t] * EE;

    // B source: W row for this lane's n (gate wv, unit j0+n)
    const short* wrow = w_cat + (size_t)(wv * HH + j0 + n) * KTOT;

    for (int k0 = 0; k0 < KTOT; k0 += BK) {
        if (k0 < HH) {
            // h part (bf16, straight copy)
            const short* src = h_in + (size_t)ab * HH + k0 + ac;
            *(short8*)&At[ar][ac]     = *(const short8*)src;
            *(short8*)&At[ar][ac + 8] = *(const short8*)(src + 8);
        } else {
            // x part: gather emb row (f32) and convert
            const float* src = emb + erow + (k0 - HH) + ac;
            float4 f0 = *(const float4*)(src);
            float4 f1 = *(const float4*)(src + 4);
            float4 f2 = *(const float4*)(src + 8);
            float4 f3 = *(const float4*)(src + 12);
            float fv[16];
            *(float4*)&fv[0]  = f0; *(float4*)&fv[4]  = f1;
            *(float4*)&fv[8]  = f2; *(float4*)&fv[12] = f3;
            short8 s0, s1;
            #pragma unroll
            for (int i = 0; i < 8; ++i) { s0[i] = f2bf(fv[i]); s1[i] = f2bf(fv[i + 8]); }
            *(short8*)&At[ar][ac]     = s0;
            *(short8*)&At[ar][ac + 8] = s1;
        }
        __syncthreads();

        #pragma unroll
        for (int ks = 0; ks < 2; ++ks) {
            short8 bfrag = *(const short8*)(wrow + k0 + ks * 32 + q * 8);
            #pragma unroll
            for (int mt = 0; mt < 4; ++mt) {
                short8 afrag = *(const short8*)&At[mt * 16 + n][ks * 32 + q * 8];
                acc[mt] = __builtin_amdgcn_mfma_f32_16x16x32_bf16(afrag, bfrag, acc[mt], 0, 0, 0);
            }
        }
        __syncthreads();
    }

    // Gate tiles -> LDS so the block can combine i,f,g,o per (b,j)
    #pragma unroll
    for (int mt = 0; mt < 4; ++mt)
        #pragma unroll
        for (int r = 0; r < 4; ++r)
            Gt[wv][mt * 16 + q * 4 + r][n] = acc[mt][r];
    __syncthreads();

    // Elementwise cell update: thread handles (m = tid>>2, 4 consecutive n)
    const int m  = tid >> 2;
    const int n4 = (tid & 3) * 4;
    const int b  = b0 + m;
    #pragma unroll
    for (int u = 0; u < 4; ++u) {
        int nn = n4 + u;
        int j  = j0 + nn;
        float ip = Gt[0][m][nn] + bias[j];
        float fp = Gt[1][m][nn] + bias[HH + j];
        float gp = Gt[2][m][nn] + bias[2 * HH + j];
        float op = Gt[3][m][nn] + bias[3 * HH + j];
        float co = c_st[(size_t)b * HH + j];
        float cn = sigf(fp) * co + sigf(ip) * tanhf(gp);
        float hn = sigf(op) * tanhf(cn);
        c_st[(size_t)b * HH + j] = cn;
        h_out[(size_t)b * HH + j] = f2bf(hn);
    }
}

// ---------------------------------------------------------------------------
// FC head: out[b] = sigmoid(dot(h[b], fc_w) + fc_b)
// ---------------------------------------------------------------------------
__global__ __launch_bounds__(256) void fc_kernel(
    const short* __restrict__ hbuf, const float* __restrict__ fc_w,
    const float* __restrict__ fc_b, float* __restrict__ out)
{
    __shared__ float red[4];
    int b = blockIdx.x;
    int tid = threadIdx.x;
    float s = 0.f;
    for (int k = tid; k < HH; k += 256)
        s += bf2f(hbuf[(size_t)b * HH + k]) * fc_w[k];
    #pragma unroll
    for (int off = 32; off > 0; off >>= 1) s += __shfl_down(s, off);
    if ((tid & 63) == 0) red[tid >> 6] = s;
    __syncthreads();
    if (tid == 0) {
        float tot = red[0] + red[1] + red[2] + red[3] + fc_b[0];
        out[b] = 1.f / (1.f + __expf(-tot));
    }
}

// ---------------------------------------------------------------------------
// Workspace layout (bytes):
//   w_cat  @ 0          : 4096*1536*2 = 12,582,912
//   bias   @ 12,582,912 : 4096*4      =     16,384
//   hbuf0  @ 12,599,296 : 256*1024*2  =    524,288
//   hbuf1  @ 13,123,584 : 256*1024*2  =    524,288
//   c      @ 13,647,872 : 256*1024*4  =  1,048,576
//   total ~14.7 MB
// ---------------------------------------------------------------------------
extern "C" void kernel_launch(void* const* d_in, const int* in_sizes, int n_in,
                              void* d_out, int out_size, void* d_ws, size_t ws_size,
                              hipStream_t stream) {
    const int*   text = (const int*)d_in[0];
    const float* emb  = (const float*)d_in[1];
    const float* w_ih = (const float*)d_in[2];
    const float* w_hh = (const float*)d_in[3];
    const float* b_ih = (const float*)d_in[4];
    const float* b_hh = (const float*)d_in[5];
    const float* fc_w = (const float*)d_in[6];
    const float* fc_b = (const float*)d_in[7];
    float* out = (float*)d_out;

    char* ws = (char*)d_ws;
    short* w_cat = (short*)(ws);
    float* bias  = (float*)(ws + 12582912);
    short* hbuf0 = (short*)(ws + 12599296);
    short* hbuf1 = (short*)(ws + 13123584);
    float* c_st  = (float*)(ws + 13647872);

    // ws is poisoned 0xAA before every timed call: zero the state we rely on
    hipMemsetAsync(hbuf0, 0, 524288, stream);
    hipMemsetAsync(c_st, 0, 1048576, stream);

    prep_kernel<<<dim3(G4), dim3(256), 0, stream>>>(w_ih, w_hh, b_ih, b_hh, w_cat, bias);

    for (int t = 0; t < TT; ++t) {
        const short* hin  = (t & 1) ? hbuf1 : hbuf0;
        short*       hout = (t & 1) ? hbuf0 : hbuf1;
        lstm_step<<<dim3(4, 64), dim3(256), 0, stream>>>(
            w_cat, bias, text, emb, hin, hout, c_st, t);
    }

    fc_kernel<<<dim3(BBATCH), dim3(256), 0, stream>>>(hbuf0, fc_w, fc_b, out);
}

// Round 2
// 4905.741 us; speedup vs baseline: 1.7092x; 1.7092x over previous
//
#include <hip/hip_runtime.h>

// Problem constants
#define TT 256
#define BB 256
#define EE 512
#define HH 1024
#define G4 4096
#define KTOT 1536
#define BK 128
#define APAD 8

typedef __attribute__((ext_vector_type(8))) short short8;
typedef __attribute__((ext_vector_type(4))) float f32x4;

__device__ __forceinline__ short f2bf(float f) {
    unsigned u; __builtin_memcpy(&u, &f, 4);
    unsigned r = (u + 0x7FFFu + ((u >> 16) & 1u)) >> 16;   // RNE
    return (short)(unsigned short)r;
}
__device__ __forceinline__ float bf2f(short s) {
    unsigned u = ((unsigned)(unsigned short)s) << 16;
    float f; __builtin_memcpy(&f, &u, 4);
    return f;
}
__device__ __forceinline__ float sigf(float x) { return 1.f / (1.f + __expf(-x)); }

// ---------------------------------------------------------------------------
// Prep: w_cat[r][0:1024]=w_hh[r], w_cat[r][1024:1536]=w_ih[r] (bf16);
//       bias[r] = b_ih[r] + b_hh[r]
// ---------------------------------------------------------------------------
__global__ __launch_bounds__(256) void prep_kernel(
    const float* __restrict__ w_ih, const float* __restrict__ w_hh,
    const float* __restrict__ b_ih, const float* __restrict__ b_hh,
    short* __restrict__ w_cat, float* __restrict__ bias)
{
    int r = blockIdx.x;
    int tid = threadIdx.x;
    for (int c = tid; c < KTOT; c += 256) {
        float v = (c < HH) ? w_hh[(size_t)r * HH + c]
                           : w_ih[(size_t)r * EE + (c - HH)];
        w_cat[(size_t)r * KTOT + c] = f2bf(v);
    }
    if (tid == 0) bias[r] = b_ih[r] + b_hh[r];
}

// ---------------------------------------------------------------------------
// Gather + convert: x_bf[t][b][:] = bf16(emb[text[b][t]][:])
// Block = 256 threads = 4 waves; each wave does one (b,t) row (512 elems).
// ---------------------------------------------------------------------------
__global__ __launch_bounds__(256) void gather_kernel(
    const int* __restrict__ text, const float* __restrict__ emb,
    short* __restrict__ xbf)
{
    int row = blockIdx.x * 4 + (threadIdx.x >> 6);   // b*TT + t
    int b = row >> 8, t = row & 255;
    int lane = threadIdx.x & 63;
    int v = text[row];
    const float* src = emb + (size_t)v * EE + lane * 8;
    float4 f0 = *(const float4*)src;
    float4 f1 = *(const float4*)(src + 4);
    float fv[8];
    *(float4*)&fv[0] = f0; *(float4*)&fv[4] = f1;
    short8 s;
    #pragma unroll
    for (int i = 0; i < 8; ++i) s[i] = f2bf(fv[i]);
    *(short8*)(xbf + ((size_t)t * BB + b) * EE + lane * 8) = s;
}

// ---------------------------------------------------------------------------
// One LSTM step. Grid 256 blocks x 256 threads (4 waves).
// Block tile: 64 batch x 16 j x 4 gates (wave g = gate g).
// XCD swizzle: blocks on XCD x share j-tiles {8x..8x+7} -> W slice 1.57 MB
// stays resident in that XCD's L2 across all 256 step launches.
// A (h|x) staged in LDS, double-buffered, 1 barrier/iter. W (B-frags) read
// directly from global (L2-hit) as 16-B loads.
// ---------------------------------------------------------------------------
__global__ __launch_bounds__(256) void lstm_step(
    const short* __restrict__ w_cat,   // [4096][1536] bf16
    const float* __restrict__ bias,    // [4096]
    const short* __restrict__ xbf,     // [T][B][E] bf16
    const short* __restrict__ h_in,    // [B][H] bf16
    short*       __restrict__ h_out,   // [B][H] bf16
    float*       __restrict__ c_st,    // [B][H] f32
    int t)
{
    __shared__ short At[2][64][BK + APAD];   // 2 x 64 x 136 bf16 = 34816 B
    __shared__ float Gt[4][64][17];          // 17408 B

    const int tid  = threadIdx.x;
    const int wv   = tid >> 6;               // gate 0..3 (i,f,g,o)
    const int lane = tid & 63;
    const int n    = lane & 15;
    const int q    = lane >> 4;

    // XCD-aware swizzle (bid % 8 = XCD, round-robin dispatch)
    const int bid = blockIdx.x;
    const int xcd = bid & 7, sub = bid >> 3;
    const int j0  = (xcd * 8 + (sub & 7)) * 16;   // 64 j-tiles
    const int b0  = (sub >> 3) * 64;              // 4 batch tiles

    const short* wrow = w_cat + (size_t)(wv * HH + j0 + n) * KTOT;

    // A staging: thread -> (row ar, cols ac..ac+31)
    const int ar = tid >> 2;
    const int ac = (tid & 3) * 32;
    const int ab = b0 + ar;
    const short* hrow = h_in + (size_t)ab * HH;
    const short* xrow = xbf + ((size_t)t * BB + ab) * EE - HH;  // index by k0>=HH

    const int kstart = (t == 0) ? HH : 0;   // h == 0 at t=0: skip h chunks
    const int niter  = (KTOT - kstart) / BK;

    f32x4 acc[4];
    #pragma unroll
    for (int i = 0; i < 4; ++i) acc[i] = (f32x4){0.f, 0.f, 0.f, 0.f};

    // Prologue: stage first chunk into buffer 0
    {
        const short* s = ((kstart < HH) ? hrow : xrow) + kstart + ac;
        *(short8*)&At[0][ar][ac]      = *(const short8*)(s);
        *(short8*)&At[0][ar][ac + 8]  = *(const short8*)(s + 8);
        *(short8*)&At[0][ar][ac + 16] = *(const short8*)(s + 16);
        *(short8*)&At[0][ar][ac + 24] = *(const short8*)(s + 24);
    }
    __syncthreads();

    for (int i = 0; i < niter; ++i) {
        const int k0  = kstart + i * BK;
        const int cur = i & 1;
        const bool more = (i + 1 < niter);
        short8 r0, r1, r2, r3;
        if (more) {   // prefetch next chunk (global) before MFMAs
            const int kn = k0 + BK;
            const short* s = ((kn < HH) ? hrow : xrow) + kn + ac;
            r0 = *(const short8*)(s);
            r1 = *(const short8*)(s + 8);
            r2 = *(const short8*)(s + 16);
            r3 = *(const short8*)(s + 24);
        }
        #pragma unroll
        for (int ks = 0; ks < 4; ++ks) {
            short8 bfrag = *(const short8*)(wrow + k0 + ks * 32 + q * 8);
            #pragma unroll
            for (int mt = 0; mt < 4; ++mt) {
                short8 afrag = *(const short8*)&At[cur][mt * 16 + n][ks * 32 + q * 8];
                acc[mt] = __builtin_amdgcn_mfma_f32_16x16x32_bf16(afrag, bfrag, acc[mt], 0, 0, 0);
            }
        }
        if (more) {
            *(short8*)&At[cur ^ 1][ar][ac]      = r0;
            *(short8*)&At[cur ^ 1][ar][ac + 8]  = r1;
            *(short8*)&At[cur ^ 1][ar][ac + 16] = r2;
            *(short8*)&At[cur ^ 1][ar][ac + 24] = r3;
            __syncthreads();   // single barrier per iter (double-buffered)
        }
    }

    // Gate exchange through LDS
    #pragma unroll
    for (int mt = 0; mt < 4; ++mt)
        #pragma unroll
        for (int r = 0; r < 4; ++r)
            Gt[wv][mt * 16 + q * 4 + r][n] = acc[mt][r];
    __syncthreads();

    // Elementwise cell update
    const int m  = tid >> 2;
    const int n4 = (tid & 3) * 4;
    const int b  = b0 + m;
    #pragma unroll
    for (int u = 0; u < 4; ++u) {
        const int nn = n4 + u;
        const int j  = j0 + nn;
        float ip = Gt[0][m][nn] + bias[j];
        float fp = Gt[1][m][nn] + bias[HH + j];
        float gp = Gt[2][m][nn] + bias[2 * HH + j];
        float op = Gt[3][m][nn] + bias[3 * HH + j];
        float co = (t == 0) ? 0.f : c_st[(size_t)b * HH + j];
        float cn = sigf(fp) * co + sigf(ip) * tanhf(gp);
        float hn = sigf(op) * tanhf(cn);
        c_st[(size_t)b * HH + j] = cn;
        h_out[(size_t)b * HH + j] = f2bf(hn);
    }
}

// ---------------------------------------------------------------------------
// FC head: out[b] = sigmoid(dot(h[b], fc_w) + fc_b)
// ---------------------------------------------------------------------------
__global__ __launch_bounds__(256) void fc_kernel(
    const short* __restrict__ hbuf, const float* __restrict__ fc_w,
    const float* __restrict__ fc_b, float* __restrict__ out)
{
    __shared__ float red[4];
    int b = blockIdx.x;
    int tid = threadIdx.x;
    float s = 0.f;
    for (int k = tid; k < HH; k += 256)
        s += bf2f(hbuf[(size_t)b * HH + k]) * fc_w[k];
    #pragma unroll
    for (int off = 32; off > 0; off >>= 1) s += __shfl_down(s, off);
    if ((tid & 63) == 0) red[tid >> 6] = s;
    __syncthreads();
    if (tid == 0) {
        float tot = red[0] + red[1] + red[2] + red[3] + fc_b[0];
        out[b] = 1.f / (1.f + __expf(-tot));
    }
}

// ---------------------------------------------------------------------------
// Workspace layout (bytes):
//   w_cat @ 0           : 4096*1536*2   = 12,582,912
//   bias  @ 12,582,912  : 4096*4        =     16,384
//   xbf   @ 12,599,296  : 256*256*512*2 = 67,108,864
//   hbuf0 @ 79,708,160  : 524,288
//   hbuf1 @ 80,232,448  : 524,288
//   c     @ 80,756,736  : 1,048,576
//   total ~81.8 MB
// ---------------------------------------------------------------------------
extern "C" void kernel_launch(void* const* d_in, const int* in_sizes, int n_in,
                              void* d_out, int out_size, void* d_ws, size_t ws_size,
                              hipStream_t stream) {
    const int*   text = (const int*)d_in[0];
    const float* emb  = (const float*)d_in[1];
    const float* w_ih = (const float*)d_in[2];
    const float* w_hh = (const float*)d_in[3];
    const float* b_ih = (const float*)d_in[4];
    const float* b_hh = (const float*)d_in[5];
    const float* fc_w = (const float*)d_in[6];
    const float* fc_b = (const float*)d_in[7];
    float* out = (float*)d_out;

    char* ws = (char*)d_ws;
    short* w_cat = (short*)(ws);
    float* bias  = (float*)(ws + 12582912);
    short* xbf   = (short*)(ws + 12599296);
    short* hbuf0 = (short*)(ws + 79708160);
    short* hbuf1 = (short*)(ws + 80232448);
    float* c_st  = (float*)(ws + 80756736);

    gather_kernel<<<dim3(BB * TT / 4), dim3(256), 0, stream>>>(text, emb, xbf);
    prep_kernel<<<dim3(G4), dim3(256), 0, stream>>>(w_ih, w_hh, b_ih, b_hh, w_cat, bias);

    for (int t = 0; t < TT; ++t) {
        const short* hin  = (t & 1) ? hbuf1 : hbuf0;
        short*       hout = (t & 1) ? hbuf0 : hbuf1;
        lstm_step<<<dim3(256), dim3(256), 0, stream>>>(
            w_cat, bias, xbf, hin, hout, c_st, t);
    }

    fc_kernel<<<dim3(BB), dim3(256), 0, stream>>>(hbuf0, fc_w, fc_b, out);
}